// Round 6
// baseline (375.921 us; speedup 1.0000x reference)
//
#include <hip/hip_runtime.h>
#include <hip/hip_bf16.h>
#include <math.h>

// Problem constants
#define B_SZ   64
#define N_SZ   1024
#define M_SZ   4096
#define HID_SZ 2048
#define OUT_SZ 512

#define AS1 __attribute__((address_space(1)))
#define AS3 __attribute__((address_space(3)))

#define NBLK 256   // fused kernel grid: 1 block/CU nominal, all co-resident

// ---------------------------------------------------------------------------
// Kernel 0: zero the grid-barrier words (ws is poisoned 0xAA every launch).
// ---------------------------------------------------------------------------
__global__ void init_kernel(unsigned* bar) {
  if (threadIdx.x < 2) bar[threadIdx.x] = 0u;
}

// ---------------------------------------------------------------------------
// Kernel 1: pairwise min-distance (unchanged).
//   xT[n][b] = min_j || pos[b,n,:] - basis[j,:] ||
// ---------------------------------------------------------------------------
__global__ __launch_bounds__(256, 2) void dist_min_kernel(
    const float* __restrict__ pos,    // [B*N][3] = [65536][3]
    const float* __restrict__ basis,  // [M][3]
    float* __restrict__ xT)           // [N][B] = [1024][64]
{
  const int tid  = threadIdx.x;
  const int lane = tid & 63;
  const int wave = tid >> 6;

  float nqx[16], nqy[16], nqz[16], qc[16];
#pragma unroll
  for (int i = 0; i < 16; ++i) {
    int j = wave * 1024 + i * 64 + lane;
    float qx = basis[3*j+0], qy = basis[3*j+1], qz = basis[3*j+2];
    nqx[i] = -qx; nqy[i] = -qy; nqz[i] = -qz;
    qc[i]  = 0.5f * (qx*qx + qy*qy + qz*qz);
  }

  __shared__ float red[16][256];
  const int pbase = blockIdx.x * 128;

  for (int c = 0; c < 8; ++c) {
    const int cbase = pbase + c * 16;
    const float* pp = pos + (size_t)3 * cbase;
    float pc[48];
#pragma unroll
    for (int e = 0; e < 48; ++e) pc[e] = pp[e];

#pragma unroll   // FULL unroll: keep pc[]/t[] indices compile-time (rule #20)
    for (int p = 0; p < 16; ++p) {
      const float px = pc[3*p+0], py = pc[3*p+1], pz = pc[3*p+2];
      float t[16];
#pragma unroll
      for (int i = 0; i < 16; ++i) t[i] = fmaf(nqx[i], px, qc[i]);
#pragma unroll
      for (int i = 0; i < 16; ++i) t[i] = fmaf(nqy[i], py, t[i]);
#pragma unroll
      for (int i = 0; i < 16; ++i) t[i] = fmaf(nqz[i], pz, t[i]);
      float m0 = fminf(fminf(t[0],  t[1]),  t[2]);
      float m1 = fminf(fminf(t[3],  t[4]),  t[5]);
      float m2 = fminf(fminf(t[6],  t[7]),  t[8]);
      float m3 = fminf(fminf(t[9],  t[10]), t[11]);
      float m4 = fminf(fminf(t[12], t[13]), t[14]);
      float r0 = fminf(fminf(m0, m1), m2);
      float r1 = fminf(fminf(m3, m4), t[15]);
      red[p][tid] = fminf(r0, r1);
    }
    __syncthreads();

    {
      const int p   = tid >> 4;
      const int sub = tid & 15;
      const float4* r4 = (const float4*)&red[p][sub * 16];
      float4 v0 = r4[0], v1 = r4[1], v2 = r4[2], v3 = r4[3];
      float w0 = fminf(fminf(v0.x, v0.y), fminf(v0.z, v0.w));
      float w1 = fminf(fminf(v1.x, v1.y), fminf(v1.z, v1.w));
      float w2 = fminf(fminf(v2.x, v2.y), fminf(v2.z, v2.w));
      float w3 = fminf(fminf(v3.x, v3.y), fminf(v3.z, v3.w));
      float v  = fminf(fminf(w0, w1), fminf(w2, w3));
#pragma unroll
      for (int o = 1; o < 16; o <<= 1) v = fminf(v, __shfl_xor(v, o));
      if (sub == 0) {
        int i = cbase + p;
        float px = pos[3*i+0], py = pos[3*i+1], pz = pos[3*i+2];
        float p2 = px*px + py*py + pz*pz;
        float d2 = fmaf(2.f, v, p2);
        d2 = fmaxf(d2, 1e-12f);
        int n = i & (N_SZ - 1);
        int b = i >> 10;
        xT[n * 64 + b] = sqrtf(d2);
      }
    }
    __syncthreads();
  }
}

// ---------------------------------------------------------------------------
// Device-scope grid barrier (generation-based; all NBLK blocks co-resident).
// ---------------------------------------------------------------------------
__device__ __forceinline__ void grid_barrier(unsigned* cnt, unsigned* gen) {
  __syncthreads();
  if (threadIdx.x == 0) {
    __threadfence();                         // release our P/x writes
    unsigned g = atomicAdd(gen, 0u);         // read generation BEFORE arriving
    unsigned a = atomicAdd(cnt, 1u);
    if (a == NBLK - 1u) {
      atomicExch(cnt, 0u);
      __threadfence();
      atomicAdd(gen, 1u);                    // release
    } else {
      while (atomicAdd(gen, 0u) == g) __builtin_amdgcn_s_sleep(2);
    }
    __threadfence();                         // acquire others' writes
  }
  __syncthreads();
}

// ---------------------------------------------------------------------------
// GEMM phase: P[s][j][b] = sum_{k in slice s} xin[k][b] * W[k][j]
// Block -> (jt = bid%JT, s = bid/JT); 64(j) x 64(b) tile; KSPAN = K/SLICES
// processed in halves of <=128 rows staged in xs; W streamed via
// global_load_lds double-buffered 16-row ring.
// ---------------------------------------------------------------------------
template <int K, int J, int JT, int SLICES>
__device__ __forceinline__ void gemm_phase(
    const float* __restrict__ xin,   // [K][64]
    const float* __restrict__ W,     // [K][J]
    float* __restrict__ P,           // [SLICES][J][64]
    float* xs, float* wring)
{
  constexpr int KSPAN = K / SLICES;
  constexpr int HALF  = (KSPAN > 128) ? 128 : KSPAN;
  constexpr int NH    = KSPAN / HALF;
  constexpr int NS    = HALF / 16;
  const int tid  = threadIdx.x;
  const int lane = tid & 63;
  const int wave = tid >> 6;
  const int jl = lane & 15;
  const int bq = lane >> 4;
  const int jt = blockIdx.x % JT;
  const int s  = blockIdx.x / JT;
  const int j0 = jt * 64 + jl * 4;
  const int b0 = wave * 16 + bq * 4;

  float acc[4][4];
#pragma unroll
  for (int a = 0; a < 4; ++a)
#pragma unroll
    for (int c = 0; c < 4; ++c) acc[a][c] = 0.f;

#pragma unroll 1
  for (int h = 0; h < NH; ++h) {
    const int kbase = s * KSPAN + h * HALF;
    // stage x half-chunk (coalesced float4)
    {
      const float4* sx = (const float4*)(xin + (size_t)kbase * 64);
      float4* dx = (float4*)xs;
#pragma unroll
      for (int i = 0; i < HALF / 16; ++i)
        dx[i * 256 + tid] = sx[i * 256 + tid];
    }
    // W staging source: lane L -> row kbase + wave*4 + (L>>4), col (L&15)*4
    const float* wsrc = W + ((size_t)(kbase + wave * 4 + (lane >> 4))) * J
                          + jt * 64 + (lane & 15) * 4;
    __builtin_amdgcn_global_load_lds((const AS1 void*)wsrc,
                                     (AS3 void*)(wring + wave * 256), 16, 0, 0);
    asm volatile("s_waitcnt vmcnt(0)" ::: "memory");
    __syncthreads();

#pragma unroll 1
    for (int t = 0; t < NS; ++t) {
      const int buf = t & 1;
      if (t + 1 < NS)
        __builtin_amdgcn_global_load_lds(
            (const AS1 void*)(wsrc + (size_t)(t + 1) * 16 * J),
            (AS3 void*)(wring + (buf ^ 1) * 1024 + wave * 256), 16, 0, 0);
#pragma unroll
      for (int r = 0; r < 16; ++r) {
        float4 w4 = *(const float4*)(wring + buf * 1024 + r * 64 + jl * 4);
        float4 x4 = *(const float4*)(xs + (t * 16 + r) * 64 + b0);
        const float wv[4] = {w4.x, w4.y, w4.z, w4.w};
        const float xv[4] = {x4.x, x4.y, x4.z, x4.w};
#pragma unroll
        for (int a = 0; a < 4; ++a)
#pragma unroll
          for (int c = 0; c < 4; ++c)
            acc[a][c] = fmaf(xv[a], wv[c], acc[a][c]);
      }
      asm volatile("s_waitcnt vmcnt(0)" ::: "memory");
      __syncthreads();
    }
  }

#pragma unroll
  for (int c = 0; c < 4; ++c) {
    float4 o = make_float4(acc[0][c], acc[1][c], acc[2][c], acc[3][c]);
    *(float4*)(P + ((size_t)s * J + (j0 + c)) * 64 + b0) = o;
  }
}

// ---------------------------------------------------------------------------
// Reduce phase: sum slices + bias (+ReLU); write xnext[j][b] or final out.
// ---------------------------------------------------------------------------
template <int J, int SLICES, bool RELU, bool FINAL>
__device__ __forceinline__ void reduce_phase(
    const float* __restrict__ P, const float* __restrict__ bias,
    float* __restrict__ out)
{
  constexpr int TOT = J * 64;
#pragma unroll 1
  for (int idx = blockIdx.x * 256 + threadIdx.x; idx < TOT; idx += NBLK * 256) {
    const int b = idx & 63;
    const int j = idx >> 6;
    float v = 0.f;
#pragma unroll
    for (int s = 0; s < SLICES; ++s) v += P[((size_t)s * J + j) * 64 + b];
    v += bias[j];
    if (RELU) v = fmaxf(v, 0.f);
    if (FINAL) out[(size_t)b * J + j] = v;
    else       out[idx] = v;
  }
}

// ---------------------------------------------------------------------------
// Fused MLP: all 4 layers + reduces in one persistent kernel, grid barriers
// between phases. 256 blocks x 256 threads; LDS 40 KB.
// ---------------------------------------------------------------------------
__global__ __launch_bounds__(256, 1) void mlp_fused_kernel(
    const float* __restrict__ x0,
    const float* __restrict__ W0, const float* __restrict__ bb0,
    const float* __restrict__ W1, const float* __restrict__ bb1,
    const float* __restrict__ W2, const float* __restrict__ bb2,
    const float* __restrict__ W3, const float* __restrict__ bb3,
    float* __restrict__ P, float* __restrict__ xh0, float* __restrict__ xh1,
    unsigned* bar, float* __restrict__ out)
{
  __shared__ __align__(16) float xs[128 * 64];        // 32 KB
  __shared__ __align__(16) float wring[2 * 16 * 64];  //  8 KB

  // L0: [64,1024] @ [1024,2048]
  gemm_phase<1024, 2048, 32, 8>(x0, W0, P, xs, wring);
  grid_barrier(bar, bar + 1);
  reduce_phase<2048, 8, true, false>(P, bb0, xh0);
  grid_barrier(bar, bar + 1);
  // L1
  gemm_phase<2048, 2048, 32, 8>(xh0, W1, P, xs, wring);
  grid_barrier(bar, bar + 1);
  reduce_phase<2048, 8, true, false>(P, bb1, xh1);
  grid_barrier(bar, bar + 1);
  // L2
  gemm_phase<2048, 2048, 32, 8>(xh1, W2, P, xs, wring);
  grid_barrier(bar, bar + 1);
  reduce_phase<2048, 8, true, false>(P, bb2, xh0);
  grid_barrier(bar, bar + 1);
  // L3: [64,2048] @ [2048,512] -> out [64][512]
  gemm_phase<2048, 512, 8, 32>(xh0, W3, P, xs, wring);
  grid_barrier(bar, bar + 1);
  reduce_phase<512, 32, false, true>(P, bb3, out);
}

// ---------------------------------------------------------------------------
extern "C" void kernel_launch(void* const* d_in, const int* in_sizes, int n_in,
                              void* d_out, int out_size, void* d_ws, size_t ws_size,
                              hipStream_t stream) {
  const float* pos   = (const float*)d_in[0];
  const float* basis = (const float*)d_in[1];
  const float* W0    = (const float*)d_in[2];
  const float* b0    = (const float*)d_in[3];
  const float* W1    = (const float*)d_in[4];
  const float* b1    = (const float*)d_in[5];
  const float* W2    = (const float*)d_in[6];
  const float* b2    = (const float*)d_in[7];
  const float* W3    = (const float*)d_in[8];
  const float* b3    = (const float*)d_in[9];
  float* out = (float*)d_out;

  char* ws = (char*)d_ws;
  float*    P   = (float*)ws;                      // 4 MiB partials
  float*    xh0 = (float*)(ws + (4u << 20));       // 512 KiB
  float*    xh1 = (float*)(ws + (4u << 20) + (512u << 10));
  float*    x0  = (float*)(ws + (5u << 20));       // 256 KiB dist output
  unsigned* bar = (unsigned*)(ws + (6u << 20));    // 2 words

  init_kernel<<<1, 64, 0, stream>>>(bar);
  dist_min_kernel<<<512, 256, 0, stream>>>(pos, basis, x0);
  mlp_fused_kernel<<<NBLK, 256, 0, stream>>>(
      x0, W0, b0, W1, b1, W2, b2, W3, b3, P, xh0, xh1, bar, out);
}

// Round 7
// 178.860 us; speedup vs baseline: 2.1018x; 2.1018x over previous
//
#include <hip/hip_runtime.h>
#include <hip/hip_bf16.h>
#include <math.h>

// Problem constants
#define B_SZ   64
#define N_SZ   1024
#define M_SZ   4096
#define HID_SZ 2048
#define OUT_SZ 512

#define AS1 __attribute__((address_space(1)))
#define AS3 __attribute__((address_space(3)))

// ---------------------------------------------------------------------------
// Kernel 1: pairwise min-distance (unchanged; correctness-proven).
//   xT[n][b] = min_j || pos[b,n,:] - basis[j,:] ||
// ---------------------------------------------------------------------------
__global__ __launch_bounds__(256, 2) void dist_min_kernel(
    const float* __restrict__ pos,    // [B*N][3] = [65536][3]
    const float* __restrict__ basis,  // [M][3]
    float* __restrict__ xT)           // [N][B] = [1024][64]
{
  const int tid  = threadIdx.x;
  const int lane = tid & 63;
  const int wave = tid >> 6;

  float nqx[16], nqy[16], nqz[16], qc[16];
#pragma unroll
  for (int i = 0; i < 16; ++i) {
    int j = wave * 1024 + i * 64 + lane;
    float qx = basis[3*j+0], qy = basis[3*j+1], qz = basis[3*j+2];
    nqx[i] = -qx; nqy[i] = -qy; nqz[i] = -qz;
    qc[i]  = 0.5f * (qx*qx + qy*qy + qz*qz);
  }

  __shared__ float red[16][256];
  const int pbase = blockIdx.x * 128;

  for (int c = 0; c < 8; ++c) {
    const int cbase = pbase + c * 16;
    const float* pp = pos + (size_t)3 * cbase;
    float pc[48];
#pragma unroll
    for (int e = 0; e < 48; ++e) pc[e] = pp[e];

#pragma unroll   // FULL unroll: keep pc[]/t[] indices compile-time (rule #20)
    for (int p = 0; p < 16; ++p) {
      const float px = pc[3*p+0], py = pc[3*p+1], pz = pc[3*p+2];
      float t[16];
#pragma unroll
      for (int i = 0; i < 16; ++i) t[i] = fmaf(nqx[i], px, qc[i]);
#pragma unroll
      for (int i = 0; i < 16; ++i) t[i] = fmaf(nqy[i], py, t[i]);
#pragma unroll
      for (int i = 0; i < 16; ++i) t[i] = fmaf(nqz[i], pz, t[i]);
      float m0 = fminf(fminf(t[0],  t[1]),  t[2]);
      float m1 = fminf(fminf(t[3],  t[4]),  t[5]);
      float m2 = fminf(fminf(t[6],  t[7]),  t[8]);
      float m3 = fminf(fminf(t[9],  t[10]), t[11]);
      float m4 = fminf(fminf(t[12], t[13]), t[14]);
      float r0 = fminf(fminf(m0, m1), m2);
      float r1 = fminf(fminf(m3, m4), t[15]);
      red[p][tid] = fminf(r0, r1);
    }
    __syncthreads();

    {
      const int p   = tid >> 4;
      const int sub = tid & 15;
      const float4* r4 = (const float4*)&red[p][sub * 16];
      float4 v0 = r4[0], v1 = r4[1], v2 = r4[2], v3 = r4[3];
      float w0 = fminf(fminf(v0.x, v0.y), fminf(v0.z, v0.w));
      float w1 = fminf(fminf(v1.x, v1.y), fminf(v1.z, v1.w));
      float w2 = fminf(fminf(v2.x, v2.y), fminf(v2.z, v2.w));
      float w3 = fminf(fminf(v3.x, v3.y), fminf(v3.z, v3.w));
      float v  = fminf(fminf(w0, w1), fminf(w2, w3));
#pragma unroll
      for (int o = 1; o < 16; o <<= 1) v = fminf(v, __shfl_xor(v, o));
      if (sub == 0) {
        int i = cbase + p;
        float px = pos[3*i+0], py = pos[3*i+1], pz = pos[3*i+2];
        float p2 = px*px + py*py + pz*pz;
        float d2 = fmaf(2.f, v, p2);
        d2 = fmaxf(d2, 1e-12f);
        int n = i & (N_SZ - 1);
        int b = i >> 10;
        xT[n * 64 + b] = sqrtf(d2);
      }
    }
    __syncthreads();
  }
}

// ---------------------------------------------------------------------------
// Kernel 2 (v4): K-split partial GEMM, COARSE W staging (few drain points).
//   P[s][j][b] = sum_{k in slice s} xT[k][b] * W[k][j]
// Block = 256 thr (4 waves), 64(j) x 64(b) tile, KSPAN k-rows per slice.
// x slice staged once (KSPAN*256B). W staged in 64-row chunks (16 KB) via
// global_load_lds, double-buffered: only KSPAN/64 + 1 vmcnt(0)+barrier
// events per block (vs 8-16 before). Compute per chunk = 1024 FMA/thread
// (~2048 cy/wave) >> DMA landing time at 2 blocks/CU -> latency hidden.
// ---------------------------------------------------------------------------
template <int K, int J, int JT, int KSPAN>
__global__ __launch_bounds__(256, 2) void gemm4_kernel(
    const float* __restrict__ xT,   // [K][64]
    const float* __restrict__ W,    // [K][J]
    float* __restrict__ P)          // [K/KSPAN][J][64]
{
  constexpr int WCHUNK = 64;
  constexpr int NSTEP  = KSPAN / WCHUNK;   // 1 or 2
  const int jt   = blockIdx.x % JT;
  const int s    = blockIdx.x / JT;
  const int tid  = threadIdx.x;
  const int lane = tid & 63;
  const int wave = tid >> 6;
  const int jl = lane & 15;
  const int bq = lane >> 4;
  const int j0 = jt * 64 + jl * 4;
  const int b0 = wave * 16 + bq * 4;

  __shared__ __align__(16) float xs[KSPAN][64];        // KSPAN*256 B
  __shared__ __align__(16) float wring[2][WCHUNK][64]; // 2 x 16 KB

  // stage x slice (coalesced float4): KSPAN*64*4 bytes / (256thr*16B) iters
  {
    const float4* sx = (const float4*)(xT + (size_t)s * KSPAN * 64);
    float4* dx = (float4*)&xs[0][0];
#pragma unroll
    for (int i = 0; i < KSPAN / 16; ++i)
      dx[i * 256 + tid] = sx[i * 256 + tid];
  }

  // W staging: wave w covers rows w*16..w*16+15 of each 64-row chunk,
  // 4 DMA instrs (4 rows each). lane L -> row +(L>>4), col (L&15)*4.
  const float* wbase = W + ((size_t)s * KSPAN + wave * 16 + (lane >> 4)) * J
                         + jt * 64 + (lane & 15) * 4;

  // prologue: stage chunk 0 into buf 0
#pragma unroll
  for (int d = 0; d < 4; ++d)
    __builtin_amdgcn_global_load_lds(
        (const AS1 void*)(wbase + (size_t)(d * 4) * J),
        (AS3 void*)&wring[0][wave * 16 + d * 4][0], 16, 0, 0);
  asm volatile("s_waitcnt vmcnt(0)" ::: "memory");
  __syncthreads();

  float acc[4][4];
#pragma unroll
  for (int a = 0; a < 4; ++a)
#pragma unroll
    for (int c = 0; c < 4; ++c) acc[a][c] = 0.f;

#pragma unroll 1
  for (int t = 0; t < NSTEP; ++t) {
    const int buf = t & 1;
    // issue next chunk's DMA first (lands under the 1024-FMA compute)
    if (t + 1 < NSTEP) {
#pragma unroll
      for (int d = 0; d < 4; ++d)
        __builtin_amdgcn_global_load_lds(
            (const AS1 void*)(wbase + (size_t)((t + 1) * WCHUNK + d * 4) * J),
            (AS3 void*)&wring[buf ^ 1][wave * 16 + d * 4][0], 16, 0, 0);
    }
    // compute 64 k-rows from current buffer
#pragma unroll 8
    for (int r = 0; r < WCHUNK; ++r) {
      float4 w4 = *(const float4*)&wring[buf][r][jl * 4];
      float4 x4 = *(const float4*)&xs[t * WCHUNK + r][b0];
      const float wv[4] = {w4.x, w4.y, w4.z, w4.w};
      const float xv[4] = {x4.x, x4.y, x4.z, x4.w};
#pragma unroll
      for (int a = 0; a < 4; ++a)
#pragma unroll
        for (int c = 0; c < 4; ++c)
          acc[a][c] = fmaf(xv[a], wv[c], acc[a][c]);
    }
    if (t + 1 < NSTEP) {
      asm volatile("s_waitcnt vmcnt(0)" ::: "memory");
      __syncthreads();
    }
  }

#pragma unroll
  for (int c = 0; c < 4; ++c) {
    float4 o = make_float4(acc[0][c], acc[1][c], acc[2][c], acc[3][c]);
    *(float4*)(P + ((size_t)s * J + (j0 + c)) * 64 + b0) = o;
  }
}

// ---------------------------------------------------------------------------
// Kernel 3: reduce K-split partials + bias (+ReLU); optional transposed write.
// ---------------------------------------------------------------------------
template <int J, int KS, bool RELU, bool TRANS>
__global__ __launch_bounds__(256) void reduce_bias_kernel(
    const float* __restrict__ P,     // [KS][J][64]
    const float* __restrict__ bias,  // [J]
    float* __restrict__ out)         // TRANS ? [J][64] : [B][J]
{
  const int t = blockIdx.x * 256 + threadIdx.x;
  const int b = t & 63;
  const int j = t >> 6;
  float v = 0.f;
#pragma unroll
  for (int s = 0; s < KS; ++s) v += P[((size_t)s * J + j) * 64 + b];
  v += bias[j];
  if (RELU) v = fmaxf(v, 0.f);
  if (TRANS) out[j * 64 + b] = v;
  else       out[(size_t)b * J + j] = v;
}

// ---------------------------------------------------------------------------
extern "C" void kernel_launch(void* const* d_in, const int* in_sizes, int n_in,
                              void* d_out, int out_size, void* d_ws, size_t ws_size,
                              hipStream_t stream) {
  const float* pos   = (const float*)d_in[0];
  const float* basis = (const float*)d_in[1];
  const float* W0    = (const float*)d_in[2];
  const float* b0    = (const float*)d_in[3];
  const float* W1    = (const float*)d_in[4];
  const float* b1    = (const float*)d_in[5];
  const float* W2    = (const float*)d_in[6];
  const float* b2    = (const float*)d_in[7];
  const float* W3    = (const float*)d_in[8];
  const float* b3    = (const float*)d_in[9];
  float* out = (float*)d_out;

  char* ws = (char*)d_ws;
  float* P  = (float*)ws;                                  // <= 8 MiB partials
  float* xA = (float*)(ws + (8u << 20));                   // 512 KiB
  float* xB = (float*)(ws + (8u << 20) + (512u << 10));    // 512 KiB

  // 1) distances + min -> xT0 [1024][64] in xA
  dist_min_kernel<<<512, 256, 0, stream>>>(pos, basis, xA);

  // 2) layer 0: [64,1024] @ [1024,2048]; KSPAN=128 -> 8 slices, 256 blocks
  gemm4_kernel<1024, HID_SZ, 32, 128>
      <<<8 * 32, 256, 0, stream>>>(xA, W0, P);
  reduce_bias_kernel<HID_SZ, 8, true, true>
      <<<HID_SZ * 64 / 256, 256, 0, stream>>>(P, b0, xB);

  // 3) layer 1: [64,2048] @ [2048,2048]; KSPAN=128 -> 16 slices, 512 blocks
  gemm4_kernel<2048, HID_SZ, 32, 128>
      <<<16 * 32, 256, 0, stream>>>(xB, W1, P);
  reduce_bias_kernel<HID_SZ, 16, true, true>
      <<<HID_SZ * 64 / 256, 256, 0, stream>>>(P, b1, xA);

  // 4) layer 2
  gemm4_kernel<2048, HID_SZ, 32, 128>
      <<<16 * 32, 256, 0, stream>>>(xA, W2, P);
  reduce_bias_kernel<HID_SZ, 16, true, true>
      <<<HID_SZ * 64 / 256, 256, 0, stream>>>(P, b2, xB);

  // 5) layer 3: [64,2048] @ [2048,512]; KSPAN=64 -> 32 slices, 256 blocks
  gemm4_kernel<2048, OUT_SZ, 8, 64>
      <<<32 * 8, 256, 0, stream>>>(xB, W3, P);
  reduce_bias_kernel<OUT_SZ, 32, false, false>
      <<<OUT_SZ * 64 / 256, 256, 0, stream>>>(P, b3, out);
}